// Round 1
// baseline (411.436 us; speedup 1.0000x reference)
//
#include <hip/hip_runtime.h>
#include <stdint.h>

#define BATCH 8
#define CH    256
#define NN    2304   // 48*48

typedef __bf16 bf16x8 __attribute__((ext_vector_type(8)));
typedef float  f32x4  __attribute__((ext_vector_type(4)));
typedef unsigned short u16x8 __attribute__((ext_vector_type(8)));
typedef unsigned int   u32x4 __attribute__((ext_vector_type(4)));

static __device__ inline unsigned short f2bf(float f) {
    __bf16 h = (__bf16)f;
    return __builtin_bit_cast(unsigned short, h);
}
static __device__ inline unsigned pk2(float a, float b) {
    return (unsigned)f2bf(a) | ((unsigned)f2bf(b) << 16);
}

// ---------------- Kernel T: transpose+cast x -> Xt[b][n][c] bf16 ; cast W ----------------
__global__ __launch_bounds__(256) void ktrans(
    const float* __restrict__ x, const float* __restrict__ Ww,
    unsigned short* __restrict__ Xt, unsigned short* __restrict__ Wbf)
{
    const int bid = blockIdx.x;
    const int t   = threadIdx.x;
    const int TPB = 4 * 36; // 64c x 64n tiles per batch
    if (bid >= BATCH * TPB) {
        const int wb = bid - BATCH * TPB;          // 0..7
        const int base = wb * 8192 + t;
        #pragma unroll
        for (int i = 0; i < 32; ++i)
            Wbf[base + i * 256] = f2bf(Ww[base + i * 256]);
        return;
    }
    const int b    = bid / TPB;
    const int tile = bid % TPB;
    const int c0   = (tile / 36) * 64;
    const int n0   = (tile % 36) * 64;
    __shared__ float ld[64][65];
    {
        const int row = t >> 2, seg = t & 3;
        const float* src = x + ((size_t)b * CH + c0 + row) * NN + n0 + seg * 16;
        #pragma unroll
        for (int q = 0; q < 4; ++q) {
            float4 v = *reinterpret_cast<const float4*>(src + q * 4);
            ld[row][seg * 16 + q * 4 + 0] = v.x;
            ld[row][seg * 16 + q * 4 + 1] = v.y;
            ld[row][seg * 16 + q * 4 + 2] = v.z;
            ld[row][seg * 16 + q * 4 + 3] = v.w;
        }
    }
    __syncthreads();
    {
        const int j = t >> 2, cs = t & 3;
        u16x8 v0, v1;
        #pragma unroll
        for (int k = 0; k < 8; ++k) v0[k] = f2bf(ld[cs * 16 + k][j]);
        #pragma unroll
        for (int k = 0; k < 8; ++k) v1[k] = f2bf(ld[cs * 16 + 8 + k][j]);
        unsigned short* dst = Xt + ((size_t)b * NN + n0 + j) * CH + c0 + cs * 16;
        *reinterpret_cast<u16x8*>(dst)     = v0;
        *reinterpret_cast<u16x8*>(dst + 8) = v1;
    }
}

// ---------------- Kernel C: Zc[b][o][n] = sum_c W[o][c] x[b][c][n]  (bf16 out) ----------------
__global__ __launch_bounds__(256) void kconv(
    const unsigned short* __restrict__ Xt,
    const unsigned short* __restrict__ Wb,
    unsigned short* __restrict__ Zc)
{
    const int bid  = blockIdx.x;   // 288 = 8b * 4ot * 9nt
    const int b    = bid & 7;
    const int rest = bid >> 3;     // 0..35
    const int ot   = rest / 9;
    const int nt   = rest % 9;
    const int tid  = threadIdx.x;
    const int lane = tid & 63, w = tid >> 6;
    const int lr = lane & 15, lg = lane >> 4;
    const int ob = ot * 64;
    const int nb = nt * 256 + w * 64;

    f32x4 acc[4][4];
    f32x4 z = {0.f, 0.f, 0.f, 0.f};
    #pragma unroll
    for (int og = 0; og < 4; ++og)
        #pragma unroll
        for (int ng = 0; ng < 4; ++ng) acc[og][ng] = z;

    const unsigned short* wp = Wb + (size_t)(ob + lr) * CH + lg * 8;
    const unsigned short* xp = Xt + ((size_t)b * NN + nb + lr) * CH + lg * 8;
    #pragma unroll 1
    for (int kc = 0; kc < 8; ++kc) {
        bf16x8 af[4], bf[4];
        #pragma unroll
        for (int og = 0; og < 4; ++og)
            af[og] = *reinterpret_cast<const bf16x8*>(wp + (size_t)og * 16 * CH + kc * 32);
        #pragma unroll
        for (int ng = 0; ng < 4; ++ng)
            bf[ng] = *reinterpret_cast<const bf16x8*>(xp + (size_t)ng * 16 * CH + kc * 32);
        #pragma unroll
        for (int og = 0; og < 4; ++og)
            #pragma unroll
            for (int ng = 0; ng < 4; ++ng)
                acc[og][ng] = __builtin_amdgcn_mfma_f32_16x16x32_bf16(af[og], bf[ng], acc[og][ng], 0, 0, 0);
    }
    #pragma unroll
    for (int og = 0; og < 4; ++og)
        #pragma unroll
        for (int ng = 0; ng < 4; ++ng)
            #pragma unroll
            for (int r = 0; r < 4; ++r)
                Zc[((size_t)b * CH + ob + og * 16 + lg * 4 + r) * NN + nb + ng * 16 + lr] =
                    f2bf(acc[og][ng][r]);
}

// ---------------- Kernel A: flash attention, swapped-QK^T, out = x + bias + Z P^T ----------------
__global__ __launch_bounds__(128) void kattn(
    const unsigned short* __restrict__ Xt,
    const unsigned short* __restrict__ Zc,
    const float* __restrict__ x,
    const float* __restrict__ bias,
    float* __restrict__ out)
{
    const int bid  = blockIdx.x;   // 576 = 8b * 72qt
    const int b    = bid & 7;      // batch -> XCD pin
    const int qt   = bid >> 3;     // 0..71
    const int tid  = threadIdx.x;
    const int lane = tid & 63;
    const int w    = tid >> 6;     // 0..1
    const int lr = lane & 15;
    const int lg = lane >> 4;
    const int nq = qt * 32 + w * 16;

    const unsigned short* xtb = Xt + (size_t)b * NN * CH;

    // Q fragments (B-operand of swapped QK^T): col = q-row
    bf16x8 qa[8];
    {
        const unsigned short* qp = xtb + (size_t)(nq + lr) * CH + lg * 8;
        #pragma unroll
        for (int kc = 0; kc < 8; ++kc)
            qa[kc] = *reinterpret_cast<const bf16x8*>(qp + kc * 32);
    }

    f32x4 acc[16];
    f32x4 zz = {0.f, 0.f, 0.f, 0.f};
    #pragma unroll
    for (int og = 0; og < 16; ++og) acc[og] = zz;
    float mrun = -1e30f, lsum = 0.f;

    const unsigned short* kp0 = xtb + (size_t)lr * CH + lg * 8;
    const unsigned short* vp0 = Zc + ((size_t)b * CH + lr) * NN + lg * 8;

    #pragma unroll 1
    for (int mb = 0; mb < NN; mb += 32) {
        // S^T tile: rows = m (32), cols = n (16).  S^T = mfma(K, Q)
        f32x4 s0 = zz, s1 = zz;
        const unsigned short* kp = kp0 + (size_t)mb * CH;
        #pragma unroll
        for (int kc = 0; kc < 8; ++kc) {
            bf16x8 k0 = *reinterpret_cast<const bf16x8*>(kp + kc * 32);
            bf16x8 k1 = *reinterpret_cast<const bf16x8*>(kp + 16 * CH + kc * 32);
            s0 = __builtin_amdgcn_mfma_f32_16x16x32_bf16(k0, qa[kc], s0, 0, 0, 0);
            s1 = __builtin_amdgcn_mfma_f32_16x16x32_bf16(k1, qa[kc], s1, 0, 0, 0);
        }
        // column (per-n) max over the 32 m's: in-lane 8 + xor16 + xor32
        float pm = fmaxf(fmaxf(fmaxf(s0[0], s0[1]), fmaxf(s0[2], s0[3])),
                         fmaxf(fmaxf(s1[0], s1[1]), fmaxf(s1[2], s1[3])));
        pm = fmaxf(pm, __shfl_xor(pm, 16));
        pm = fmaxf(pm, __shfl_xor(pm, 32));
        if (__any(pm > mrun + 8.f)) {   // defer-max, THR = 8
            float mn = fmaxf(mrun, pm);
            float alpha = __expf(mrun - mn);
            mrun = mn;
            lsum *= alpha;
            #pragma unroll
            for (int og = 0; og < 16; ++og) {
                acc[og][0] *= alpha; acc[og][1] *= alpha;
                acc[og][2] *= alpha; acc[og][3] *= alpha;
            }
        }
        float p0[4], p1[4];
        float rs = 0.f;
        #pragma unroll
        for (int r = 0; r < 4; ++r) {
            p0[r] = __expf(s0[r] - mrun);
            p1[r] = __expf(s1[r] - mrun);
            rs += p0[r] + p1[r];
        }
        rs += __shfl_xor(rs, 16);
        rs += __shfl_xor(rs, 32);
        lsum += rs;
        // Build P^T B-fragment in-register via 8 shuffles:
        // lane needs P[m=8*lg+j][n=lr]; holder of m: group m/4 (p0) or (m-16)/4 (p1), reg m%4.
        unsigned u0 = pk2(p0[0], p0[1]), u1 = pk2(p0[2], p0[3]);
        unsigned u2 = pk2(p1[0], p1[1]), u3 = pk2(p1[2], p1[3]);
        int s0l = lr + ((lg & 1) << 5);
        unsigned a0 = (unsigned)__shfl((int)u0, s0l),      c0 = (unsigned)__shfl((int)u2, s0l);
        unsigned a1 = (unsigned)__shfl((int)u1, s0l),      c1 = (unsigned)__shfl((int)u3, s0l);
        unsigned a2 = (unsigned)__shfl((int)u0, s0l + 16), c2 = (unsigned)__shfl((int)u2, s0l + 16);
        unsigned a3 = (unsigned)__shfl((int)u1, s0l + 16), c3 = (unsigned)__shfl((int)u3, s0l + 16);
        bool hi = (lg >= 2);
        u32x4 pw;
        pw[0] = hi ? c0 : a0;
        pw[1] = hi ? c1 : a1;
        pw[2] = hi ? c2 : a2;
        pw[3] = hi ? c3 : a3;
        bf16x8 pb = __builtin_bit_cast(bf16x8, pw);
        // PV: y^T[o][n] += V^T[o][m] * P^T[m][n]
        const unsigned short* vp = vp0 + mb;
        #pragma unroll
        for (int og = 0; og < 16; ++og) {
            bf16x8 vb = *reinterpret_cast<const bf16x8*>(vp + (size_t)og * 16 * NN);
            acc[og] = __builtin_amdgcn_mfma_f32_16x16x32_bf16(vb, pb, acc[og], 0, 0, 0);
        }
    }
    // epilogue: out[b][o][n] = acc/lsum + bias[o] + x[b][o][n]
    float inv = 1.f / lsum;
    #pragma unroll
    for (int og = 0; og < 16; ++og) {
        #pragma unroll
        for (int r = 0; r < 4; ++r) {
            int o = og * 16 + lg * 4 + r;
            size_t idx = ((size_t)b * CH + o) * NN + nq + lr;
            out[idx] = acc[og][r] * inv + bias[o] + x[idx];
        }
    }
}

extern "C" void kernel_launch(void* const* d_in, const int* in_sizes, int n_in,
                              void* d_out, int out_size, void* d_ws, size_t ws_size,
                              hipStream_t stream) {
    const float* x    = (const float*)d_in[0];
    const float* Ww   = (const float*)d_in[1];
    const float* bias = (const float*)d_in[2];
    float* out = (float*)d_out;

    unsigned short* Xt  = (unsigned short*)d_ws;                 // B*N*C bf16
    unsigned short* Zc  = Xt + (size_t)BATCH * NN * CH;          // B*C*N bf16
    unsigned short* Wbf = Zc + (size_t)BATCH * NN * CH;          // C*C bf16

    ktrans<<<8 * 144 + 8, 256, 0, stream>>>(x, Ww, Xt, Wbf);
    kconv <<<288,        256, 0, stream>>>(Xt, Wbf, Zc);
    kattn <<<576,        128, 0, stream>>>(Xt, Zc, x, bias, out);
}

// Round 2
// 362.501 us; speedup vs baseline: 1.1350x; 1.1350x over previous
//
#include <hip/hip_runtime.h>
#include <stdint.h>

#define BATCH 8
#define CH    256
#define NN    2304   // 48*48
#define NCHUNK 4
#define CLEN  (NN / NCHUNK)   // 576 keys per kv-chunk

typedef __bf16 bf16x8 __attribute__((ext_vector_type(8)));
typedef float  f32x4  __attribute__((ext_vector_type(4)));
typedef unsigned short u16x8 __attribute__((ext_vector_type(8)));
typedef unsigned int   u32x4 __attribute__((ext_vector_type(4)));

static __device__ inline unsigned short f2bf(float f) {
    __bf16 h = (__bf16)f;
    return __builtin_bit_cast(unsigned short, h);
}
static __device__ inline unsigned pk2(float a, float b) {
    return (unsigned)f2bf(a) | ((unsigned)f2bf(b) << 16);
}

// ---------------- Kernel T: transpose+cast x -> Xt[b][n][c] bf16 ; cast W ----------------
__global__ __launch_bounds__(256) void ktrans(
    const float* __restrict__ x, const float* __restrict__ Ww,
    unsigned short* __restrict__ Xt, unsigned short* __restrict__ Wbf)
{
    const int bid = blockIdx.x;
    const int t   = threadIdx.x;
    const int TPB = 4 * 36; // 64c x 64n tiles per batch
    if (bid >= BATCH * TPB) {
        const int wb = bid - BATCH * TPB;          // 0..7
        const int base = wb * 8192 + t;
        #pragma unroll
        for (int i = 0; i < 32; ++i)
            Wbf[base + i * 256] = f2bf(Ww[base + i * 256]);
        return;
    }
    const int b    = bid / TPB;
    const int tile = bid % TPB;
    const int c0   = (tile / 36) * 64;
    const int n0   = (tile % 36) * 64;
    __shared__ float ld[64][65];
    {
        const int row = t >> 2, seg = t & 3;
        const float* src = x + ((size_t)b * CH + c0 + row) * NN + n0 + seg * 16;
        #pragma unroll
        for (int q = 0; q < 4; ++q) {
            float4 v = *reinterpret_cast<const float4*>(src + q * 4);
            ld[row][seg * 16 + q * 4 + 0] = v.x;
            ld[row][seg * 16 + q * 4 + 1] = v.y;
            ld[row][seg * 16 + q * 4 + 2] = v.z;
            ld[row][seg * 16 + q * 4 + 3] = v.w;
        }
    }
    __syncthreads();
    {
        const int j = t >> 2, cs = t & 3;
        u16x8 v0, v1;
        #pragma unroll
        for (int k = 0; k < 8; ++k) v0[k] = f2bf(ld[cs * 16 + k][j]);
        #pragma unroll
        for (int k = 0; k < 8; ++k) v1[k] = f2bf(ld[cs * 16 + 8 + k][j]);
        unsigned short* dst = Xt + ((size_t)b * NN + n0 + j) * CH + c0 + cs * 16;
        *reinterpret_cast<u16x8*>(dst)     = v0;
        *reinterpret_cast<u16x8*>(dst + 8) = v1;
    }
}

// ---------------- Kernel C: Zc[b][o][n] = sum_c W[o][c] x[b][c][n]  (bf16 out) ----------------
__global__ __launch_bounds__(256) void kconv(
    const unsigned short* __restrict__ Xt,
    const unsigned short* __restrict__ Wb,
    unsigned short* __restrict__ Zc)
{
    const int bid  = blockIdx.x;   // 288 = 8b * 4ot * 9nt
    const int b    = bid & 7;
    const int rest = bid >> 3;     // 0..35
    const int ot   = rest / 9;
    const int nt   = rest % 9;
    const int tid  = threadIdx.x;
    const int lane = tid & 63, w = tid >> 6;
    const int lr = lane & 15, lg = lane >> 4;
    const int ob = ot * 64;
    const int nb = nt * 256 + w * 64;

    f32x4 acc[4][4];
    f32x4 z = {0.f, 0.f, 0.f, 0.f};
    #pragma unroll
    for (int og = 0; og < 4; ++og)
        #pragma unroll
        for (int ng = 0; ng < 4; ++ng) acc[og][ng] = z;

    const unsigned short* wp = Wb + (size_t)(ob + lr) * CH + lg * 8;
    const unsigned short* xp = Xt + ((size_t)b * NN + nb + lr) * CH + lg * 8;
    #pragma unroll 1
    for (int kc = 0; kc < 8; ++kc) {
        bf16x8 af[4], bf[4];
        #pragma unroll
        for (int og = 0; og < 4; ++og)
            af[og] = *reinterpret_cast<const bf16x8*>(wp + (size_t)og * 16 * CH + kc * 32);
        #pragma unroll
        for (int ng = 0; ng < 4; ++ng)
            bf[ng] = *reinterpret_cast<const bf16x8*>(xp + (size_t)ng * 16 * CH + kc * 32);
        #pragma unroll
        for (int og = 0; og < 4; ++og)
            #pragma unroll
            for (int ng = 0; ng < 4; ++ng)
                acc[og][ng] = __builtin_amdgcn_mfma_f32_16x16x32_bf16(af[og], bf[ng], acc[og][ng], 0, 0, 0);
    }
    #pragma unroll
    for (int og = 0; og < 4; ++og)
        #pragma unroll
        for (int ng = 0; ng < 4; ++ng)
            #pragma unroll
            for (int r = 0; r < 4; ++r)
                Zc[((size_t)b * CH + ob + og * 16 + lg * 4 + r) * NN + nb + ng * 16 + lr] =
                    f2bf(acc[og][ng][r]);
}

// ---------------- Kernel A: flash attention, in-block split-KV x4 ----------------
// 1152 blocks (8 batch * 144 q-tiles), 256 threads = 4 waves.
// Wave w processes keys [w*576, (w+1)*576) for the block's 16 q-rows;
// partial (m, l, acc) merged through LDS (fp32-exact).
__global__ __launch_bounds__(256) void kattn(
    const unsigned short* __restrict__ Xt,
    const unsigned short* __restrict__ Zc,
    const float* __restrict__ x,
    const float* __restrict__ bias,
    float* __restrict__ out)
{
    const int bid  = blockIdx.x;   // 1152 = 8b * 144qt
    const int b    = bid & 7;      // batch -> XCD pin
    const int qt   = bid >> 3;     // 0..143
    const int tid  = threadIdx.x;
    const int lane = tid & 63;
    const int w    = tid >> 6;     // kv-chunk 0..3
    const int lr = lane & 15;
    const int lg = lane >> 4;
    const int nq = qt * 16;

    __shared__ float ml[NCHUNK][2][16];
    __shared__ float lacc[16][260];   // [n][o], padded stride vs 256

    const unsigned short* xtb = Xt + (size_t)b * NN * CH;

    // Q fragments (B-operand of swapped QK^T): col = q-row
    bf16x8 qa[8];
    {
        const unsigned short* qp = xtb + (size_t)(nq + lr) * CH + lg * 8;
        #pragma unroll
        for (int kc = 0; kc < 8; ++kc)
            qa[kc] = *reinterpret_cast<const bf16x8*>(qp + kc * 32);
    }

    f32x4 acc[16];
    f32x4 zz = {0.f, 0.f, 0.f, 0.f};
    #pragma unroll
    for (int og = 0; og < 16; ++og) acc[og] = zz;
    float mrun = -1e30f, lsum = 0.f;

    const unsigned short* kp0 = xtb + (size_t)lr * CH + lg * 8;
    const unsigned short* vp0 = Zc + ((size_t)b * CH + lr) * NN + lg * 8;

    const int m0 = w * CLEN, m1 = m0 + CLEN;
    #pragma unroll 1
    for (int mb = m0; mb < m1; mb += 32) {
        // S^T tile: rows = m (32), cols = n (16).  S^T = mfma(K, Q)
        f32x4 s0 = zz, s1 = zz;
        const unsigned short* kp = kp0 + (size_t)mb * CH;
        #pragma unroll
        for (int kc = 0; kc < 8; ++kc) {
            bf16x8 k0 = *reinterpret_cast<const bf16x8*>(kp + kc * 32);
            bf16x8 k1 = *reinterpret_cast<const bf16x8*>(kp + 16 * CH + kc * 32);
            s0 = __builtin_amdgcn_mfma_f32_16x16x32_bf16(k0, qa[kc], s0, 0, 0, 0);
            s1 = __builtin_amdgcn_mfma_f32_16x16x32_bf16(k1, qa[kc], s1, 0, 0, 0);
        }
        // column (per-n) max over the 32 m's: in-lane 8 + xor16 + xor32
        float pm = fmaxf(fmaxf(fmaxf(s0[0], s0[1]), fmaxf(s0[2], s0[3])),
                         fmaxf(fmaxf(s1[0], s1[1]), fmaxf(s1[2], s1[3])));
        pm = fmaxf(pm, __shfl_xor(pm, 16));
        pm = fmaxf(pm, __shfl_xor(pm, 32));
        if (__any(pm > mrun + 8.f)) {   // defer-max, THR = 8
            float mn = fmaxf(mrun, pm);
            float alpha = __expf(mrun - mn);
            mrun = mn;
            lsum *= alpha;
            #pragma unroll
            for (int og = 0; og < 16; ++og) {
                acc[og][0] *= alpha; acc[og][1] *= alpha;
                acc[og][2] *= alpha; acc[og][3] *= alpha;
            }
        }
        float p0[4], p1[4];
        float rs = 0.f;
        #pragma unroll
        for (int r = 0; r < 4; ++r) {
            p0[r] = __expf(s0[r] - mrun);
            p1[r] = __expf(s1[r] - mrun);
            rs += p0[r] + p1[r];
        }
        rs += __shfl_xor(rs, 16);
        rs += __shfl_xor(rs, 32);
        lsum += rs;
        // Build P^T B-fragment in-register via 8 shuffles:
        // lane needs P[m=8*lg+j][n=lr]; holder of m: group m/4 (p0) or (m-16)/4 (p1), reg m%4.
        unsigned u0 = pk2(p0[0], p0[1]), u1 = pk2(p0[2], p0[3]);
        unsigned u2 = pk2(p1[0], p1[1]), u3 = pk2(p1[2], p1[3]);
        int s0l = lr + ((lg & 1) << 5);
        unsigned a0 = (unsigned)__shfl((int)u0, s0l),      c0 = (unsigned)__shfl((int)u2, s0l);
        unsigned a1 = (unsigned)__shfl((int)u1, s0l),      c1 = (unsigned)__shfl((int)u3, s0l);
        unsigned a2 = (unsigned)__shfl((int)u0, s0l + 16), c2 = (unsigned)__shfl((int)u2, s0l + 16);
        unsigned a3 = (unsigned)__shfl((int)u1, s0l + 16), c3 = (unsigned)__shfl((int)u3, s0l + 16);
        bool hi = (lg >= 2);
        u32x4 pw;
        pw[0] = hi ? c0 : a0;
        pw[1] = hi ? c1 : a1;
        pw[2] = hi ? c2 : a2;
        pw[3] = hi ? c3 : a3;
        bf16x8 pb = __builtin_bit_cast(bf16x8, pw);
        // PV: y^T[o][n] += V^T[o][m] * P^T[m][n]
        const unsigned short* vp = vp0 + mb;
        #pragma unroll
        for (int og = 0; og < 16; ++og) {
            bf16x8 vb = *reinterpret_cast<const bf16x8*>(vp + (size_t)og * 16 * NN);
            acc[og] = __builtin_amdgcn_mfma_f32_16x16x32_bf16(vb, pb, acc[og], 0, 0, 0);
        }
    }

    // ---- in-block combine of the 4 kv-chunk flash states (fp32-exact) ----
    if (lg == 0) { ml[w][0][lr] = mrun; ml[w][1][lr] = lsum; }
    __syncthreads();
    float M = fmaxf(fmaxf(ml[0][0][lr], ml[1][0][lr]),
                    fmaxf(ml[2][0][lr], ml[3][0][lr]));
    float L = 0.f;
    #pragma unroll
    for (int c = 0; c < NCHUNK; ++c)
        L += __expf(ml[c][0][lr] - M) * ml[c][1][lr];
    const float wc = __expf(mrun - M);
    #pragma unroll
    for (int og = 0; og < 16; ++og) {
        acc[og][0] *= wc; acc[og][1] *= wc;
        acc[og][2] *= wc; acc[og][3] *= wc;
    }
    #pragma unroll 1
    for (int c = 0; c < NCHUNK; ++c) {
        if (w == c) {
            #pragma unroll
            for (int og = 0; og < 16; ++og) {
                float* p = &lacc[lr][og * 16 + lg * 4];
                if (c == 0) {
                    *reinterpret_cast<f32x4*>(p) = acc[og];
                } else {
                    f32x4 v = *reinterpret_cast<f32x4*>(p);
                    v[0] += acc[og][0]; v[1] += acc[og][1];
                    v[2] += acc[og][2]; v[3] += acc[og][3];
                    *reinterpret_cast<f32x4*>(p) = v;
                }
            }
        }
        __syncthreads();
    }

    // epilogue: wave w writes o-range [w*64, w*64+64)
    const float inv = 1.f / L;
    #pragma unroll
    for (int og4 = 0; og4 < 4; ++og4) {
        const int og = w * 4 + og4;
        f32x4 v = *reinterpret_cast<f32x4*>(&lacc[lr][og * 16 + lg * 4]);
        #pragma unroll
        for (int r = 0; r < 4; ++r) {
            const int o = og * 16 + lg * 4 + r;
            const size_t idx = ((size_t)b * CH + o) * NN + nq + lr;
            out[idx] = v[r] * inv + bias[o] + x[idx];
        }
    }
}

extern "C" void kernel_launch(void* const* d_in, const int* in_sizes, int n_in,
                              void* d_out, int out_size, void* d_ws, size_t ws_size,
                              hipStream_t stream) {
    const float* x    = (const float*)d_in[0];
    const float* Ww   = (const float*)d_in[1];
    const float* bias = (const float*)d_in[2];
    float* out = (float*)d_out;

    unsigned short* Xt  = (unsigned short*)d_ws;                 // B*N*C bf16
    unsigned short* Zc  = Xt + (size_t)BATCH * NN * CH;          // B*C*N bf16
    unsigned short* Wbf = Zc + (size_t)BATCH * NN * CH;          // C*C bf16

    ktrans<<<8 * 144 + 8, 256, 0, stream>>>(x, Ww, Xt, Wbf);
    kconv <<<288,        256, 0, stream>>>(Xt, Wbf, Zc);
    kattn <<<1152,       256, 0, stream>>>(Xt, Zc, x, bias, out);
}

// Round 3
// 353.802 us; speedup vs baseline: 1.1629x; 1.0246x over previous
//
#include <hip/hip_runtime.h>
#include <stdint.h>

#define BATCH 8
#define CH    256
#define NN    2304   // 48*48
#define NCHUNK 4
#define CLEN  (NN / NCHUNK)   // 576 keys per kv-chunk

typedef __bf16 bf16x8 __attribute__((ext_vector_type(8)));
typedef float  f32x4  __attribute__((ext_vector_type(4)));
typedef unsigned short u16x8 __attribute__((ext_vector_type(8)));
typedef unsigned int   u32x4 __attribute__((ext_vector_type(4)));

static __device__ inline unsigned short f2bf(float f) {
    __bf16 h = (__bf16)f;
    return __builtin_bit_cast(unsigned short, h);
}
static __device__ inline unsigned pk2(float a, float b) {
    return (unsigned)f2bf(a) | ((unsigned)f2bf(b) << 16);
}

// ---------------- Kernel T: transpose+cast x -> Xt[b][n][c] bf16 ; cast W ----------------
__global__ __launch_bounds__(256) void ktrans(
    const float* __restrict__ x, const float* __restrict__ Ww,
    unsigned short* __restrict__ Xt, unsigned short* __restrict__ Wbf)
{
    const int bid = blockIdx.x;
    const int t   = threadIdx.x;
    const int TPB = 4 * 36; // 64c x 64n tiles per batch
    if (bid >= BATCH * TPB) {
        const int wb = bid - BATCH * TPB;          // 0..7
        const int base = wb * 8192 + t;
        #pragma unroll
        for (int i = 0; i < 32; ++i)
            Wbf[base + i * 256] = f2bf(Ww[base + i * 256]);
        return;
    }
    const int b    = bid / TPB;
    const int tile = bid % TPB;
    const int c0   = (tile / 36) * 64;
    const int n0   = (tile % 36) * 64;
    __shared__ float ld[64][65];
    {
        const int row = t >> 2, seg = t & 3;
        const float* src = x + ((size_t)b * CH + c0 + row) * NN + n0 + seg * 16;
        #pragma unroll
        for (int q = 0; q < 4; ++q) {
            float4 v = *reinterpret_cast<const float4*>(src + q * 4);
            ld[row][seg * 16 + q * 4 + 0] = v.x;
            ld[row][seg * 16 + q * 4 + 1] = v.y;
            ld[row][seg * 16 + q * 4 + 2] = v.z;
            ld[row][seg * 16 + q * 4 + 3] = v.w;
        }
    }
    __syncthreads();
    {
        const int j = t >> 2, cs = t & 3;
        u16x8 v0, v1;
        #pragma unroll
        for (int k = 0; k < 8; ++k) v0[k] = f2bf(ld[cs * 16 + k][j]);
        #pragma unroll
        for (int k = 0; k < 8; ++k) v1[k] = f2bf(ld[cs * 16 + 8 + k][j]);
        unsigned short* dst = Xt + ((size_t)b * NN + n0 + j) * CH + c0 + cs * 16;
        *reinterpret_cast<u16x8*>(dst)     = v0;
        *reinterpret_cast<u16x8*>(dst + 8) = v1;
    }
}

// ---------------- Kernel C: Zc[b][o][n] = sum_c W[o][c] x[b][c][n]  (bf16 out) ----------------
__global__ __launch_bounds__(256) void kconv(
    const unsigned short* __restrict__ Xt,
    const unsigned short* __restrict__ Wb,
    unsigned short* __restrict__ Zc)
{
    const int bid  = blockIdx.x;   // 288 = 8b * 4ot * 9nt
    const int b    = bid & 7;
    const int rest = bid >> 3;     // 0..35
    const int ot   = rest / 9;
    const int nt   = rest % 9;
    const int tid  = threadIdx.x;
    const int lane = tid & 63, w = tid >> 6;
    const int lr = lane & 15, lg = lane >> 4;
    const int ob = ot * 64;
    const int nb = nt * 256 + w * 64;

    f32x4 acc[4][4];
    f32x4 z = {0.f, 0.f, 0.f, 0.f};
    #pragma unroll
    for (int og = 0; og < 4; ++og)
        #pragma unroll
        for (int ng = 0; ng < 4; ++ng) acc[og][ng] = z;

    const unsigned short* wp = Wb + (size_t)(ob + lr) * CH + lg * 8;
    const unsigned short* xp = Xt + ((size_t)b * NN + nb + lr) * CH + lg * 8;
    #pragma unroll 1
    for (int kc = 0; kc < 8; ++kc) {
        bf16x8 af[4], bf[4];
        #pragma unroll
        for (int og = 0; og < 4; ++og)
            af[og] = *reinterpret_cast<const bf16x8*>(wp + (size_t)og * 16 * CH + kc * 32);
        #pragma unroll
        for (int ng = 0; ng < 4; ++ng)
            bf[ng] = *reinterpret_cast<const bf16x8*>(xp + (size_t)ng * 16 * CH + kc * 32);
        #pragma unroll
        for (int og = 0; og < 4; ++og)
            #pragma unroll
            for (int ng = 0; ng < 4; ++ng)
                acc[og][ng] = __builtin_amdgcn_mfma_f32_16x16x32_bf16(af[og], bf[ng], acc[og][ng], 0, 0, 0);
    }
    #pragma unroll
    for (int og = 0; og < 4; ++og)
        #pragma unroll
        for (int ng = 0; ng < 4; ++ng)
            #pragma unroll
            for (int r = 0; r < 4; ++r)
                Zc[((size_t)b * CH + ob + og * 16 + lg * 4 + r) * NN + nb + ng * 16 + lr] =
                    f2bf(acc[og][ng][r]);
}

// ---------------- Kernel A: flash attention, split-KV x4, register-batched + pipelined loads ----------------
__global__ __launch_bounds__(256, 2) void kattn(
    const unsigned short* __restrict__ Xt,
    const unsigned short* __restrict__ Zc,
    const float* __restrict__ x,
    const float* __restrict__ bias,
    float* __restrict__ out)
{
    const int bid  = blockIdx.x;   // 1152 = 8b * 144qt
    const int b    = bid & 7;      // batch -> XCD pin
    const int qt   = bid >> 3;     // 0..143
    const int tid  = threadIdx.x;
    const int lane = tid & 63;
    const int w    = tid >> 6;     // kv-chunk 0..3
    const int lr = lane & 15;
    const int lg = lane >> 4;
    const int nq = qt * 16;

    __shared__ float ml[NCHUNK][2][16];
    __shared__ float lacc[16][260];   // [n][o], padded stride vs 256

    const unsigned short* xtb = Xt + (size_t)b * NN * CH;

    // Q fragments (B-operand of swapped QK^T): col = q-row
    bf16x8 qa[8];
    {
        const unsigned short* qp = xtb + (size_t)(nq + lr) * CH + lg * 8;
        #pragma unroll
        for (int kc = 0; kc < 8; ++kc)
            qa[kc] = *reinterpret_cast<const bf16x8*>(qp + kc * 32);
    }

    f32x4 acc[16];
    f32x4 zz = {0.f, 0.f, 0.f, 0.f};
    #pragma unroll
    for (int og = 0; og < 16; ++og) acc[og] = zz;
    float mrun = -1e30f, lsum = 0.f;

    const unsigned short* kp0 = xtb + (size_t)lr * CH + lg * 8;
    const unsigned short* vp0 = Zc + ((size_t)b * CH + lr) * NN + lg * 8;

    const int m0 = w * CLEN, m1 = m0 + CLEN;

    // prologue: batch-load first K tile into registers
    bf16x8 kf[16];
    {
        const unsigned short* kp = kp0 + (size_t)m0 * CH;
        #pragma unroll
        for (int kc = 0; kc < 8; ++kc) {
            kf[kc]     = *reinterpret_cast<const bf16x8*>(kp + kc * 32);
            kf[8 + kc] = *reinterpret_cast<const bf16x8*>(kp + 16 * CH + kc * 32);
        }
    }

    #pragma unroll 1
    for (int mb = m0; mb < m1; mb += 32) {
        // issue V tile loads early (consumed after softmax)
        bf16x8 vf[16];
        {
            const unsigned short* vp = vp0 + mb;
            #pragma unroll
            for (int og = 0; og < 16; ++og)
                vf[og] = *reinterpret_cast<const bf16x8*>(vp + (size_t)og * 16 * NN);
        }
        // S^T tile: rows = m (32), cols = n (16).  S^T = mfma(K, Q)
        f32x4 s0 = zz, s1 = zz;
        #pragma unroll
        for (int kc = 0; kc < 8; ++kc) {
            s0 = __builtin_amdgcn_mfma_f32_16x16x32_bf16(kf[kc],     qa[kc], s0, 0, 0, 0);
            s1 = __builtin_amdgcn_mfma_f32_16x16x32_bf16(kf[8 + kc], qa[kc], s1, 0, 0, 0);
        }
        // column (per-n) max over the 32 m's: in-lane 8 + xor16 + xor32
        float pm = fmaxf(fmaxf(fmaxf(s0[0], s0[1]), fmaxf(s0[2], s0[3])),
                         fmaxf(fmaxf(s1[0], s1[1]), fmaxf(s1[2], s1[3])));
        pm = fmaxf(pm, __shfl_xor(pm, 16));
        pm = fmaxf(pm, __shfl_xor(pm, 32));
        if (__any(pm > mrun + 8.f)) {   // defer-max, THR = 8
            float mn = fmaxf(mrun, pm);
            float alpha = __expf(mrun - mn);
            mrun = mn;
            lsum *= alpha;
            #pragma unroll
            for (int og = 0; og < 16; ++og) {
                acc[og][0] *= alpha; acc[og][1] *= alpha;
                acc[og][2] *= alpha; acc[og][3] *= alpha;
            }
        }
        float p0[4], p1[4];
        float rs = 0.f;
        #pragma unroll
        for (int r = 0; r < 4; ++r) {
            p0[r] = __expf(s0[r] - mrun);
            p1[r] = __expf(s1[r] - mrun);
            rs += p0[r] + p1[r];
        }
        rs += __shfl_xor(rs, 16);
        rs += __shfl_xor(rs, 32);
        lsum += rs;
        // Build P^T B-fragment in-register via 8 shuffles:
        unsigned u0 = pk2(p0[0], p0[1]), u1 = pk2(p0[2], p0[3]);
        unsigned u2 = pk2(p1[0], p1[1]), u3 = pk2(p1[2], p1[3]);
        int s0l = lr + ((lg & 1) << 5);
        unsigned a0 = (unsigned)__shfl((int)u0, s0l),      c0 = (unsigned)__shfl((int)u2, s0l);
        unsigned a1 = (unsigned)__shfl((int)u1, s0l),      c1 = (unsigned)__shfl((int)u3, s0l);
        unsigned a2 = (unsigned)__shfl((int)u0, s0l + 16), c2 = (unsigned)__shfl((int)u2, s0l + 16);
        unsigned a3 = (unsigned)__shfl((int)u1, s0l + 16), c3 = (unsigned)__shfl((int)u3, s0l + 16);
        bool hi = (lg >= 2);
        u32x4 pw;
        pw[0] = hi ? c0 : a0;
        pw[1] = hi ? c1 : a1;
        pw[2] = hi ? c2 : a2;
        pw[3] = hi ? c3 : a3;
        bf16x8 pb = __builtin_bit_cast(bf16x8, pw);

        // prefetch next K tile into (now dead) kf registers
        if (mb + 32 < m1) {
            const unsigned short* kp = kp0 + (size_t)(mb + 32) * CH;
            #pragma unroll
            for (int kc = 0; kc < 8; ++kc) {
                kf[kc]     = *reinterpret_cast<const bf16x8*>(kp + kc * 32);
                kf[8 + kc] = *reinterpret_cast<const bf16x8*>(kp + 16 * CH + kc * 32);
            }
        }

        // PV: y^T[o][n] += V^T[o][m] * P^T[m][n]
        #pragma unroll
        for (int og = 0; og < 16; ++og)
            acc[og] = __builtin_amdgcn_mfma_f32_16x16x32_bf16(vf[og], pb, acc[og], 0, 0, 0);
    }

    // ---- in-block combine of the 4 kv-chunk flash states (fp32-exact) ----
    if (lg == 0) { ml[w][0][lr] = mrun; ml[w][1][lr] = lsum; }
    __syncthreads();
    float M = fmaxf(fmaxf(ml[0][0][lr], ml[1][0][lr]),
                    fmaxf(ml[2][0][lr], ml[3][0][lr]));
    float L = 0.f;
    #pragma unroll
    for (int c = 0; c < NCHUNK; ++c)
        L += __expf(ml[c][0][lr] - M) * ml[c][1][lr];
    const float wc = __expf(mrun - M);
    #pragma unroll
    for (int og = 0; og < 16; ++og) {
        acc[og][0] *= wc; acc[og][1] *= wc;
        acc[og][2] *= wc; acc[og][3] *= wc;
    }
    #pragma unroll 1
    for (int c = 0; c < NCHUNK; ++c) {
        if (w == c) {
            #pragma unroll
            for (int og = 0; og < 16; ++og) {
                float* p = &lacc[lr][og * 16 + lg * 4];
                if (c == 0) {
                    *reinterpret_cast<f32x4*>(p) = acc[og];
                } else {
                    f32x4 v = *reinterpret_cast<f32x4*>(p);
                    v[0] += acc[og][0]; v[1] += acc[og][1];
                    v[2] += acc[og][2]; v[3] += acc[og][3];
                    *reinterpret_cast<f32x4*>(p) = v;
                }
            }
        }
        __syncthreads();
    }

    // epilogue: wave w writes o-range [w*64, w*64+64)
    const float inv = 1.f / L;
    #pragma unroll
    for (int og4 = 0; og4 < 4; ++og4) {
        const int og = w * 4 + og4;
        f32x4 v = *reinterpret_cast<f32x4*>(&lacc[lr][og * 16 + lg * 4]);
        #pragma unroll
        for (int r = 0; r < 4; ++r) {
            const int o = og * 16 + lg * 4 + r;
            const size_t idx = ((size_t)b * CH + o) * NN + nq + lr;
            out[idx] = v[r] * inv + bias[o] + x[idx];
        }
    }
}

extern "C" void kernel_launch(void* const* d_in, const int* in_sizes, int n_in,
                              void* d_out, int out_size, void* d_ws, size_t ws_size,
                              hipStream_t stream) {
    const float* x    = (const float*)d_in[0];
    const float* Ww   = (const float*)d_in[1];
    const float* bias = (const float*)d_in[2];
    float* out = (float*)d_out;

    unsigned short* Xt  = (unsigned short*)d_ws;                 // B*N*C bf16
    unsigned short* Zc  = Xt + (size_t)BATCH * NN * CH;          // B*C*N bf16
    unsigned short* Wbf = Zc + (size_t)BATCH * NN * CH;          // C*C bf16

    ktrans<<<8 * 144 + 8, 256, 0, stream>>>(x, Ww, Xt, Wbf);
    kconv <<<288,        256, 0, stream>>>(Xt, Wbf, Zc);
    kattn <<<1152,       256, 0, stream>>>(Xt, Zc, x, bias, out);
}

// Round 4
// 352.609 us; speedup vs baseline: 1.1668x; 1.0034x over previous
//
#include <hip/hip_runtime.h>
#include <stdint.h>

#define BATCH 8
#define CH    256
#define NN    2304   // 48*48
#define NCHUNK 4
#define CLEN  (NN / NCHUNK)   // 576 keys per kv-chunk

typedef __bf16 bf16x8 __attribute__((ext_vector_type(8)));
typedef float  f32x4  __attribute__((ext_vector_type(4)));
typedef unsigned short u16x8 __attribute__((ext_vector_type(8)));
typedef unsigned int   u32x4 __attribute__((ext_vector_type(4)));

static __device__ inline unsigned short f2bf(float f) {
    __bf16 h = (__bf16)f;
    return __builtin_bit_cast(unsigned short, h);
}
static __device__ inline unsigned pk2(float a, float b) {
    return (unsigned)f2bf(a) | ((unsigned)f2bf(b) << 16);
}

// ---------------- Kernel T: transpose+cast x -> Xt[b][n][c] bf16 ; cast W ----------------
__global__ __launch_bounds__(256) void ktrans(
    const float* __restrict__ x, const float* __restrict__ Ww,
    unsigned short* __restrict__ Xt, unsigned short* __restrict__ Wbf)
{
    const int bid = blockIdx.x;
    const int t   = threadIdx.x;
    const int TPB = 4 * 36; // 64c x 64n tiles per batch
    if (bid >= BATCH * TPB) {
        const int wb = bid - BATCH * TPB;          // 0..7
        const int base = wb * 8192 + t;
        #pragma unroll
        for (int i = 0; i < 32; ++i)
            Wbf[base + i * 256] = f2bf(Ww[base + i * 256]);
        return;
    }
    const int b    = bid / TPB;
    const int tile = bid % TPB;
    const int c0   = (tile / 36) * 64;
    const int n0   = (tile % 36) * 64;
    __shared__ float ld[64][65];
    {
        const int row = t >> 2, seg = t & 3;
        const float* src = x + ((size_t)b * CH + c0 + row) * NN + n0 + seg * 16;
        #pragma unroll
        for (int q = 0; q < 4; ++q) {
            float4 v = *reinterpret_cast<const float4*>(src + q * 4);
            ld[row][seg * 16 + q * 4 + 0] = v.x;
            ld[row][seg * 16 + q * 4 + 1] = v.y;
            ld[row][seg * 16 + q * 4 + 2] = v.z;
            ld[row][seg * 16 + q * 4 + 3] = v.w;
        }
    }
    __syncthreads();
    {
        const int j = t >> 2, cs = t & 3;
        u16x8 v0, v1;
        #pragma unroll
        for (int k = 0; k < 8; ++k) v0[k] = f2bf(ld[cs * 16 + k][j]);
        #pragma unroll
        for (int k = 0; k < 8; ++k) v1[k] = f2bf(ld[cs * 16 + 8 + k][j]);
        unsigned short* dst = Xt + ((size_t)b * NN + n0 + j) * CH + c0 + cs * 16;
        *reinterpret_cast<u16x8*>(dst)     = v0;
        *reinterpret_cast<u16x8*>(dst + 8) = v1;
    }
}

// ---------------- Kernel C: Zc[b][o][n] = sum_c W[o][c] x[b][c][n]  (bf16 out) ----------------
__global__ __launch_bounds__(256) void kconv(
    const unsigned short* __restrict__ Xt,
    const unsigned short* __restrict__ Wb,
    unsigned short* __restrict__ Zc)
{
    const int bid  = blockIdx.x;   // 288 = 8b * 4ot * 9nt
    const int b    = bid & 7;
    const int rest = bid >> 3;     // 0..35
    const int ot   = rest / 9;
    const int nt   = rest % 9;
    const int tid  = threadIdx.x;
    const int lane = tid & 63, w = tid >> 6;
    const int lr = lane & 15, lg = lane >> 4;
    const int ob = ot * 64;
    const int nb = nt * 256 + w * 64;

    f32x4 acc[4][4];
    f32x4 z = {0.f, 0.f, 0.f, 0.f};
    #pragma unroll
    for (int og = 0; og < 4; ++og)
        #pragma unroll
        for (int ng = 0; ng < 4; ++ng) acc[og][ng] = z;

    const unsigned short* wp = Wb + (size_t)(ob + lr) * CH + lg * 8;
    const unsigned short* xp = Xt + ((size_t)b * NN + nb + lr) * CH + lg * 8;
    #pragma unroll 1
    for (int kc = 0; kc < 8; ++kc) {
        bf16x8 af[4], bf[4];
        #pragma unroll
        for (int og = 0; og < 4; ++og)
            af[og] = *reinterpret_cast<const bf16x8*>(wp + (size_t)og * 16 * CH + kc * 32);
        #pragma unroll
        for (int ng = 0; ng < 4; ++ng)
            bf[ng] = *reinterpret_cast<const bf16x8*>(xp + (size_t)ng * 16 * CH + kc * 32);
        #pragma unroll
        for (int og = 0; og < 4; ++og)
            #pragma unroll
            for (int ng = 0; ng < 4; ++ng)
                acc[og][ng] = __builtin_amdgcn_mfma_f32_16x16x32_bf16(af[og], bf[ng], acc[og][ng], 0, 0, 0);
    }
    #pragma unroll
    for (int og = 0; og < 4; ++og)
        #pragma unroll
        for (int ng = 0; ng < 4; ++ng)
            #pragma unroll
            for (int r = 0; r < 4; ++r)
                Zc[((size_t)b * CH + ob + og * 16 + lg * 4 + r) * NN + nb + ng * 16 + lr] =
                    f2bf(acc[og][ng][r]);
}

// ---------------- Kernel A: flash attention, split-KV x4, pinned load pipeline ----------------
__global__ __launch_bounds__(256, 2) void kattn(
    const unsigned short* __restrict__ Xt,
    const unsigned short* __restrict__ Zc,
    const float* __restrict__ x,
    const float* __restrict__ bias,
    float* __restrict__ out)
{
    const int bid  = blockIdx.x;   // 1152 = 8b * 144qt
    const int b    = bid & 7;      // batch -> XCD pin
    const int qt   = bid >> 3;     // 0..143
    const int tid  = threadIdx.x;
    const int lane = tid & 63;
    const int w    = tid >> 6;     // kv-chunk 0..3
    const int lr = lane & 15;
    const int lg = lane >> 4;
    const int nq = qt * 16;

    __shared__ float ml[NCHUNK][2][16];
    __shared__ float lacc[16][260];   // [n][o], padded stride vs 256

    const unsigned short* xtb = Xt + (size_t)b * NN * CH;

    // Q fragments (B-operand of swapped QK^T): col = q-row
    bf16x8 qa[8];
    {
        const unsigned short* qp = xtb + (size_t)(nq + lr) * CH + lg * 8;
        #pragma unroll
        for (int kc = 0; kc < 8; ++kc)
            qa[kc] = *reinterpret_cast<const bf16x8*>(qp + kc * 32);
    }

    f32x4 acc[16];
    f32x4 zz = {0.f, 0.f, 0.f, 0.f};
    #pragma unroll
    for (int og = 0; og < 16; ++og) acc[og] = zz;
    float mrun = -1e30f, lsum = 0.f;

    const unsigned short* kp0 = xtb + (size_t)lr * CH + lg * 8;
    const unsigned short* vp0 = Zc + ((size_t)b * CH + lr) * NN + lg * 8;

    const int m0 = w * CLEN, m1 = m0 + CLEN;

    // prologue: batch-load first K tile into registers
    bf16x8 kf[16];
    {
        const unsigned short* kp = kp0 + (size_t)m0 * CH;
        #pragma unroll
        for (int kc = 0; kc < 8; ++kc) {
            kf[kc]     = *reinterpret_cast<const bf16x8*>(kp + kc * 32);
            kf[8 + kc] = *reinterpret_cast<const bf16x8*>(kp + 16 * CH + kc * 32);
        }
    }
    __builtin_amdgcn_sched_barrier(0);

    #pragma unroll 1
    for (int mb = m0; mb < m1; mb += 32) {
        // ---- phase 1: issue V tile loads (in flight across QK^T + softmax) ----
        bf16x8 vf[16];
        {
            const unsigned short* vp = vp0 + mb;
            #pragma unroll
            for (int og = 0; og < 16; ++og)
                vf[og] = *reinterpret_cast<const bf16x8*>(vp + (size_t)og * 16 * NN);
        }
        __builtin_amdgcn_sched_barrier(0);

        // ---- phase 2: S^T = mfma(K, Q) ----
        f32x4 s0 = zz, s1 = zz;
        __builtin_amdgcn_s_setprio(1);
        #pragma unroll
        for (int kc = 0; kc < 8; ++kc) {
            s0 = __builtin_amdgcn_mfma_f32_16x16x32_bf16(kf[kc],     qa[kc], s0, 0, 0, 0);
            s1 = __builtin_amdgcn_mfma_f32_16x16x32_bf16(kf[8 + kc], qa[kc], s1, 0, 0, 0);
        }
        __builtin_amdgcn_s_setprio(0);
        __builtin_amdgcn_sched_barrier(0);

        // ---- phase 3: online softmax (kf registers are dead now) ----
        float pm = fmaxf(fmaxf(fmaxf(s0[0], s0[1]), fmaxf(s0[2], s0[3])),
                         fmaxf(fmaxf(s1[0], s1[1]), fmaxf(s1[2], s1[3])));
        pm = fmaxf(pm, __shfl_xor(pm, 16));
        pm = fmaxf(pm, __shfl_xor(pm, 32));
        if (__any(pm > mrun + 8.f)) {   // defer-max, THR = 8
            float mn = fmaxf(mrun, pm);
            float alpha = __expf(mrun - mn);
            mrun = mn;
            lsum *= alpha;
            #pragma unroll
            for (int og = 0; og < 16; ++og) {
                acc[og][0] *= alpha; acc[og][1] *= alpha;
                acc[og][2] *= alpha; acc[og][3] *= alpha;
            }
        }
        float p0[4], p1[4];
        float rs = 0.f;
        #pragma unroll
        for (int r = 0; r < 4; ++r) {
            p0[r] = __expf(s0[r] - mrun);
            p1[r] = __expf(s1[r] - mrun);
            rs += p0[r] + p1[r];
        }
        rs += __shfl_xor(rs, 16);
        rs += __shfl_xor(rs, 32);
        lsum += rs;
        // Build P^T B-fragment in-register via 8 shuffles:
        unsigned u0 = pk2(p0[0], p0[1]), u1 = pk2(p0[2], p0[3]);
        unsigned u2 = pk2(p1[0], p1[1]), u3 = pk2(p1[2], p1[3]);
        int s0l = lr + ((lg & 1) << 5);
        unsigned a0 = (unsigned)__shfl((int)u0, s0l),      c0 = (unsigned)__shfl((int)u2, s0l);
        unsigned a1 = (unsigned)__shfl((int)u1, s0l),      c1 = (unsigned)__shfl((int)u3, s0l);
        unsigned a2 = (unsigned)__shfl((int)u0, s0l + 16), c2 = (unsigned)__shfl((int)u2, s0l + 16);
        unsigned a3 = (unsigned)__shfl((int)u1, s0l + 16), c3 = (unsigned)__shfl((int)u3, s0l + 16);
        bool hi = (lg >= 2);
        u32x4 pw;
        pw[0] = hi ? c0 : a0;
        pw[1] = hi ? c1 : a1;
        pw[2] = hi ? c2 : a2;
        pw[3] = hi ? c3 : a3;
        bf16x8 pb = __builtin_bit_cast(bf16x8, pw);
        __builtin_amdgcn_sched_barrier(0);

        // ---- phase 4: prefetch next K tile (in flight across PV) ----
        if (mb + 32 < m1) {
            const unsigned short* kp = kp0 + (size_t)(mb + 32) * CH;
            #pragma unroll
            for (int kc = 0; kc < 8; ++kc) {
                kf[kc]     = *reinterpret_cast<const bf16x8*>(kp + kc * 32);
                kf[8 + kc] = *reinterpret_cast<const bf16x8*>(kp + 16 * CH + kc * 32);
            }
        }
        __builtin_amdgcn_sched_barrier(0);

        // ---- phase 5: PV: y^T[o][n] += V^T[o][m] * P^T[m][n] ----
        __builtin_amdgcn_s_setprio(1);
        #pragma unroll
        for (int og = 0; og < 16; ++og)
            acc[og] = __builtin_amdgcn_mfma_f32_16x16x32_bf16(vf[og], pb, acc[og], 0, 0, 0);
        __builtin_amdgcn_s_setprio(0);
        __builtin_amdgcn_sched_barrier(0);
    }

    // ---- in-block combine of the 4 kv-chunk flash states (fp32-exact) ----
    if (lg == 0) { ml[w][0][lr] = mrun; ml[w][1][lr] = lsum; }
    __syncthreads();
    float M = fmaxf(fmaxf(ml[0][0][lr], ml[1][0][lr]),
                    fmaxf(ml[2][0][lr], ml[3][0][lr]));
    float L = 0.f;
    #pragma unroll
    for (int c = 0; c < NCHUNK; ++c)
        L += __expf(ml[c][0][lr] - M) * ml[c][1][lr];
    const float wc = __expf(mrun - M);
    #pragma unroll
    for (int og = 0; og < 16; ++og) {
        acc[og][0] *= wc; acc[og][1] *= wc;
        acc[og][2] *= wc; acc[og][3] *= wc;
    }
    #pragma unroll 1
    for (int c = 0; c < NCHUNK; ++c) {
        if (w == c) {
            #pragma unroll
            for (int og = 0; og < 16; ++og) {
                float* p = &lacc[lr][og * 16 + lg * 4];
                if (c == 0) {
                    *reinterpret_cast<f32x4*>(p) = acc[og];
                } else {
                    f32x4 v = *reinterpret_cast<f32x4*>(p);
                    v[0] += acc[og][0]; v[1] += acc[og][1];
                    v[2] += acc[og][2]; v[3] += acc[og][3];
                    *reinterpret_cast<f32x4*>(p) = v;
                }
            }
        }
        __syncthreads();
    }

    // epilogue: wave w writes o-range [w*64, w*64+64)
    const float inv = 1.f / L;
    #pragma unroll
    for (int og4 = 0; og4 < 4; ++og4) {
        const int og = w * 4 + og4;
        f32x4 v = *reinterpret_cast<f32x4*>(&lacc[lr][og * 16 + lg * 4]);
        #pragma unroll
        for (int r = 0; r < 4; ++r) {
            const int o = og * 16 + lg * 4 + r;
            const size_t idx = ((size_t)b * CH + o) * NN + nq + lr;
            out[idx] = v[r] * inv + bias[o] + x[idx];
        }
    }
}

extern "C" void kernel_launch(void* const* d_in, const int* in_sizes, int n_in,
                              void* d_out, int out_size, void* d_ws, size_t ws_size,
                              hipStream_t stream) {
    const float* x    = (const float*)d_in[0];
    const float* Ww   = (const float*)d_in[1];
    const float* bias = (const float*)d_in[2];
    float* out = (float*)d_out;

    unsigned short* Xt  = (unsigned short*)d_ws;                 // B*N*C bf16
    unsigned short* Zc  = Xt + (size_t)BATCH * NN * CH;          // B*C*N bf16
    unsigned short* Wbf = Zc + (size_t)BATCH * NN * CH;          // C*C bf16

    ktrans<<<8 * 144 + 8, 256, 0, stream>>>(x, Ww, Xt, Wbf);
    kconv <<<288,        256, 0, stream>>>(Xt, Wbf, Zc);
    kattn <<<1152,       256, 0, stream>>>(Xt, Zc, x, bias, out);
}

// Round 5
// 155.661 us; speedup vs baseline: 2.6432x; 2.2652x over previous
//
#include <hip/hip_runtime.h>
#include <stdint.h>

#define BATCH 8
#define CH    256
#define NN    2304   // 48*48
#define KVB   32
#define NT    (NN / KVB)   // 72 kv-tiles

typedef __bf16 bf16x8 __attribute__((ext_vector_type(8)));
typedef float  f32x4  __attribute__((ext_vector_type(4)));
typedef unsigned short u16x8 __attribute__((ext_vector_type(8)));
typedef unsigned int   u32x4 __attribute__((ext_vector_type(4)));

static __device__ inline unsigned short f2bf(float f) {
    __bf16 h = (__bf16)f;
    return __builtin_bit_cast(unsigned short, h);
}
static __device__ inline unsigned pk2(float a, float b) {
    return (unsigned)f2bf(a) | ((unsigned)f2bf(b) << 16);
}

#define GLOAD_LDS(gp, lp) __builtin_amdgcn_global_load_lds( \
    (const __attribute__((address_space(1))) unsigned int*)(gp), \
    (__attribute__((address_space(3))) unsigned int*)(lp), 16, 0, 0)

// ---------------- Kernel T: transpose+cast x -> Xt[b][n][c] bf16 ; cast W ----------------
__global__ __launch_bounds__(256) void ktrans(
    const float* __restrict__ x, const float* __restrict__ Ww,
    unsigned short* __restrict__ Xt, unsigned short* __restrict__ Wbf)
{
    const int bid = blockIdx.x;
    const int t   = threadIdx.x;
    const int TPB = 4 * 36; // 64c x 64n tiles per batch
    if (bid >= BATCH * TPB) {
        const int wb = bid - BATCH * TPB;          // 0..7
        const int base = wb * 8192 + t;
        #pragma unroll
        for (int i = 0; i < 32; ++i)
            Wbf[base + i * 256] = f2bf(Ww[base + i * 256]);
        return;
    }
    const int b    = bid / TPB;
    const int tile = bid % TPB;
    const int c0   = (tile / 36) * 64;
    const int n0   = (tile % 36) * 64;
    __shared__ float ld[64][65];
    {
        const int row = t >> 2, seg = t & 3;
        const float* src = x + ((size_t)b * CH + c0 + row) * NN + n0 + seg * 16;
        #pragma unroll
        for (int q = 0; q < 4; ++q) {
            float4 v = *reinterpret_cast<const float4*>(src + q * 4);
            ld[row][seg * 16 + q * 4 + 0] = v.x;
            ld[row][seg * 16 + q * 4 + 1] = v.y;
            ld[row][seg * 16 + q * 4 + 2] = v.z;
            ld[row][seg * 16 + q * 4 + 3] = v.w;
        }
    }
    __syncthreads();
    {
        const int j = t >> 2, cs = t & 3;
        u16x8 v0, v1;
        #pragma unroll
        for (int k = 0; k < 8; ++k) v0[k] = f2bf(ld[cs * 16 + k][j]);
        #pragma unroll
        for (int k = 0; k < 8; ++k) v1[k] = f2bf(ld[cs * 16 + 8 + k][j]);
        unsigned short* dst = Xt + ((size_t)b * NN + n0 + j) * CH + c0 + cs * 16;
        *reinterpret_cast<u16x8*>(dst)     = v0;
        *reinterpret_cast<u16x8*>(dst + 8) = v1;
    }
}

// ---------------- Kernel C: Zc[b][o][n] = sum_c W[o][c] x[b][c][n]  (bf16 out) ----------------
__global__ __launch_bounds__(256) void kconv(
    const unsigned short* __restrict__ Xt,
    const unsigned short* __restrict__ Wb,
    unsigned short* __restrict__ Zc)
{
    const int bid  = blockIdx.x;   // 288 = 8b * 4ot * 9nt
    const int b    = bid & 7;
    const int rest = bid >> 3;     // 0..35
    const int ot   = rest / 9;
    const int nt   = rest % 9;
    const int tid  = threadIdx.x;
    const int lane = tid & 63, w = tid >> 6;
    const int lr = lane & 15, lg = lane >> 4;
    const int ob = ot * 64;
    const int nb = nt * 256 + w * 64;

    f32x4 acc[4][4];
    f32x4 z = {0.f, 0.f, 0.f, 0.f};
    #pragma unroll
    for (int og = 0; og < 4; ++og)
        #pragma unroll
        for (int ng = 0; ng < 4; ++ng) acc[og][ng] = z;

    const unsigned short* wp = Wb + (size_t)(ob + lr) * CH + lg * 8;
    const unsigned short* xp = Xt + ((size_t)b * NN + nb + lr) * CH + lg * 8;
    #pragma unroll 1
    for (int kc = 0; kc < 8; ++kc) {
        bf16x8 af[4], bf[4];
        #pragma unroll
        for (int og = 0; og < 4; ++og)
            af[og] = *reinterpret_cast<const bf16x8*>(wp + (size_t)og * 16 * CH + kc * 32);
        #pragma unroll
        for (int ng = 0; ng < 4; ++ng)
            bf[ng] = *reinterpret_cast<const bf16x8*>(xp + (size_t)ng * 16 * CH + kc * 32);
        #pragma unroll
        for (int og = 0; og < 4; ++og)
            #pragma unroll
            for (int ng = 0; ng < 4; ++ng)
                acc[og][ng] = __builtin_amdgcn_mfma_f32_16x16x32_bf16(af[og], bf[ng], acc[og][ng], 0, 0, 0);
    }
    #pragma unroll
    for (int og = 0; og < 4; ++og)
        #pragma unroll
        for (int ng = 0; ng < 4; ++ng)
            #pragma unroll
            for (int r = 0; r < 4; ++r)
                Zc[((size_t)b * CH + ob + og * 16 + lg * 4 + r) * NN + nb + ng * 16 + lr] =
                    f2bf(acc[og][ng][r]);
}

// ---------------- Kernel A: flash attention, LDS-staged K/V (global_load_lds), dbuf ----------------
// 288 blocks (8 batch * 36 q-tiles of 64 rows), 4 waves; wave owns 16 q-rows over ALL keys.
// K tile [32][512B] swz ^(row&7)<<4 ; V tile [256][64B] swz ^(o&3)<<4.
// Linear LDS dest + inverse-swizzled global source + swizzled ds_read (rule #21).
__global__ __launch_bounds__(256, 2) void kattn(
    const unsigned short* __restrict__ Xt,
    const unsigned short* __restrict__ Zc,
    const float* __restrict__ x,
    const float* __restrict__ bias,
    float* __restrict__ out)
{
    __shared__ __attribute__((aligned(16))) unsigned char smem[2][32768];

    const int bid  = blockIdx.x;   // 288 = 8b * 36qt
    const int b    = bid & 7;      // batch -> XCD pin
    const int qt   = bid >> 3;     // 0..35
    const int tid  = threadIdx.x;
    const int lane = tid & 63;
    const int w    = tid >> 6;     // wave 0..3 -> q-subtile
    const int lr = lane & 15;
    const int lg = lane >> 4;
    const int nq = qt * 64 + w * 16;

    const unsigned short* xtb = Xt + (size_t)b * NN * CH;
    const char* kSrc = (const char*)xtb;                                  // + n*512 bytes
    const char* vSrc = (const char*)(Zc + (size_t)b * CH * NN);           // + o*4608 bytes

    // per-lane staging offsets (loop-invariant)
    int koff[4], voff[4];
    #pragma unroll
    for (int i = 0; i < 4; ++i) {
        int p = w * 4096 + i * 1024 + lane * 16;
        int krow = p >> 9, kc_ = p & 511;
        koff[i] = krow * 512 + (kc_ ^ ((krow & 7) << 4));
        int o = p >> 6, vc = p & 63;
        voff[i] = o * 4608 + (vc ^ ((o & 3) << 4));
    }

    // Q fragments (B-operand of swapped QK^T)
    bf16x8 qa[8];
    {
        const unsigned short* qp = xtb + (size_t)(nq + lr) * CH + lg * 8;
        #pragma unroll
        for (int kc = 0; kc < 8; ++kc)
            qa[kc] = *reinterpret_cast<const bf16x8*>(qp + kc * 32);
    }

    f32x4 acc[16];
    f32x4 zz = {0.f, 0.f, 0.f, 0.f};
    #pragma unroll
    for (int og = 0; og < 16; ++og) acc[og] = zz;
    float mrun = -1e30f, lsum = 0.f;

    const int kx = (lr & 7) << 4;
    const int vx = (lg * 16) ^ ((lr & 3) << 4);

    // prologue: stage tile 0 into buf 0
    {
        const char* ks = kSrc;
        const char* vs = vSrc;
        unsigned char* kb = &smem[0][w * 4096];
        unsigned char* vb = &smem[0][16384 + w * 4096];
        #pragma unroll
        for (int i = 0; i < 4; ++i) GLOAD_LDS(ks + koff[i], kb + i * 1024);
        #pragma unroll
        for (int i = 0; i < 4; ++i) GLOAD_LDS(vs + voff[i], vb + i * 1024);
    }
    __syncthreads();

    int cur = 0;
    #pragma unroll 1
    for (int ti = 0; ti < NT; ++ti) {
        const int mb = ti * KVB;
        // stage next tile into the other buffer (no wait here)
        if (ti + 1 < NT) {
            const char* ks = kSrc + (size_t)(mb + KVB) * 512;
            const char* vs = vSrc + (size_t)(mb + KVB) * 2;
            unsigned char* kb = &smem[cur ^ 1][w * 4096];
            unsigned char* vb = &smem[cur ^ 1][16384 + w * 4096];
            #pragma unroll
            for (int i = 0; i < 4; ++i) GLOAD_LDS(ks + koff[i], kb + i * 1024);
            #pragma unroll
            for (int i = 0; i < 4; ++i) GLOAD_LDS(vs + voff[i], vb + i * 1024);
        }

        const unsigned char* kbuf = smem[cur];
        const unsigned char* vbuf = smem[cur] + 16384;

        // S^T = mfma(K, Q): rows = m (32 keys), cols = n (16 q)
        f32x4 s0 = zz, s1 = zz;
        #pragma unroll
        for (int kc = 0; kc < 8; ++kc) {
            bf16x8 k0 = *reinterpret_cast<const bf16x8*>(kbuf + lr * 512        + ((lg * 16 + kc * 64) ^ kx));
            bf16x8 k1 = *reinterpret_cast<const bf16x8*>(kbuf + (lr + 16) * 512 + ((lg * 16 + kc * 64) ^ kx));
            s0 = __builtin_amdgcn_mfma_f32_16x16x32_bf16(k0, qa[kc], s0, 0, 0, 0);
            s1 = __builtin_amdgcn_mfma_f32_16x16x32_bf16(k1, qa[kc], s1, 0, 0, 0);
        }

        // online softmax (per-q-column over the 32 keys)
        float pm = fmaxf(fmaxf(fmaxf(s0[0], s0[1]), fmaxf(s0[2], s0[3])),
                         fmaxf(fmaxf(s1[0], s1[1]), fmaxf(s1[2], s1[3])));
        pm = fmaxf(pm, __shfl_xor(pm, 16));
        pm = fmaxf(pm, __shfl_xor(pm, 32));
        if (__any(pm > mrun + 8.f)) {   // defer-max, THR = 8
            float mn = fmaxf(mrun, pm);
            float alpha = __expf(mrun - mn);
            mrun = mn;
            lsum *= alpha;
            #pragma unroll
            for (int og = 0; og < 16; ++og) {
                acc[og][0] *= alpha; acc[og][1] *= alpha;
                acc[og][2] *= alpha; acc[og][3] *= alpha;
            }
        }
        float p0[4], p1[4];
        float rs = 0.f;
        #pragma unroll
        for (int r = 0; r < 4; ++r) {
            p0[r] = __expf(s0[r] - mrun);
            p1[r] = __expf(s1[r] - mrun);
            rs += p0[r] + p1[r];
        }
        rs += __shfl_xor(rs, 16);
        rs += __shfl_xor(rs, 32);
        lsum += rs;
        // Build P^T B-fragment in-register via 8 shuffles
        unsigned u0 = pk2(p0[0], p0[1]), u1 = pk2(p0[2], p0[3]);
        unsigned u2 = pk2(p1[0], p1[1]), u3 = pk2(p1[2], p1[3]);
        int s0l = lr + ((lg & 1) << 5);
        unsigned a0 = (unsigned)__shfl((int)u0, s0l),      c0 = (unsigned)__shfl((int)u2, s0l);
        unsigned a1 = (unsigned)__shfl((int)u1, s0l),      c1 = (unsigned)__shfl((int)u3, s0l);
        unsigned a2 = (unsigned)__shfl((int)u0, s0l + 16), c2 = (unsigned)__shfl((int)u2, s0l + 16);
        unsigned a3 = (unsigned)__shfl((int)u1, s0l + 16), c3 = (unsigned)__shfl((int)u3, s0l + 16);
        bool hi = (lg >= 2);
        u32x4 pw;
        pw[0] = hi ? c0 : a0;
        pw[1] = hi ? c1 : a1;
        pw[2] = hi ? c2 : a2;
        pw[3] = hi ? c3 : a3;
        bf16x8 pb = __builtin_bit_cast(bf16x8, pw);

        // PV: y^T[o][n] += V^T[o][m] * P^T[m][n]
        #pragma unroll
        for (int og = 0; og < 16; ++og) {
            bf16x8 vb = *reinterpret_cast<const bf16x8*>(vbuf + (og * 16 + lr) * 64 + vx);
            acc[og] = __builtin_amdgcn_mfma_f32_16x16x32_bf16(vb, pb, acc[og], 0, 0, 0);
        }

        __syncthreads();
        cur ^= 1;
    }

    // epilogue: out[b][o][nq+lr] = acc/lsum + bias[o] + x
    const float inv = 1.f / lsum;
    #pragma unroll
    for (int og = 0; og < 16; ++og) {
        #pragma unroll
        for (int r = 0; r < 4; ++r) {
            const int o = og * 16 + lg * 4 + r;
            const size_t idx = ((size_t)b * CH + o) * NN + nq + lr;
            out[idx] = acc[og][r] * inv + bias[o] + x[idx];
        }
    }
}

extern "C" void kernel_launch(void* const* d_in, const int* in_sizes, int n_in,
                              void* d_out, int out_size, void* d_ws, size_t ws_size,
                              hipStream_t stream) {
    const float* x    = (const float*)d_in[0];
    const float* Ww   = (const float*)d_in[1];
    const float* bias = (const float*)d_in[2];
    float* out = (float*)d_out;

    unsigned short* Xt  = (unsigned short*)d_ws;                 // B*N*C bf16
    unsigned short* Zc  = Xt + (size_t)BATCH * NN * CH;          // B*C*N bf16
    unsigned short* Wbf = Zc + (size_t)BATCH * NN * CH;          // C*C bf16

    ktrans<<<8 * 144 + 8, 256, 0, stream>>>(x, Ww, Xt, Wbf);
    kconv <<<288,        256, 0, stream>>>(Xt, Wbf, Zc);
    kattn <<<288,        256, 0, stream>>>(Xt, Zc, x, bias, out);
}

// Round 6
// 121.978 us; speedup vs baseline: 3.3730x; 1.2761x over previous
//
#include <hip/hip_runtime.h>
#include <stdint.h>

#define BATCH 8
#define CH    256
#define NN    2304   // 48*48
#define KVB   32
#define KVH   1152   // keys per kv-half
#define NIT   (KVH / KVB)   // 36 iterations

typedef __bf16 bf16x8 __attribute__((ext_vector_type(8)));
typedef float  f32x4  __attribute__((ext_vector_type(4)));
typedef unsigned short u16x8 __attribute__((ext_vector_type(8)));
typedef unsigned int   u32x4 __attribute__((ext_vector_type(4)));

static __device__ inline unsigned short f2bf(float f) {
    __bf16 h = (__bf16)f;
    return __builtin_bit_cast(unsigned short, h);
}
static __device__ inline unsigned pk2(float a, float b) {
    return (unsigned)f2bf(a) | ((unsigned)f2bf(b) << 16);
}
static __device__ inline float bf2f(unsigned short u) {
    unsigned v = (unsigned)u << 16;
    return __builtin_bit_cast(float, v);
}

#define GLOAD_LDS(gp, lp) __builtin_amdgcn_global_load_lds( \
    (const __attribute__((address_space(1))) unsigned int*)(gp), \
    (__attribute__((address_space(3))) unsigned int*)(lp), 16, 0, 0)

// ---------------- Kernel T: transpose+cast x -> Xt[b][n][c] bf16 ; cast W ----------------
__global__ __launch_bounds__(256) void ktrans(
    const float* __restrict__ x, const float* __restrict__ Ww,
    unsigned short* __restrict__ Xt, unsigned short* __restrict__ Wbf)
{
    const int bid = blockIdx.x;
    const int t   = threadIdx.x;
    const int TPB = 4 * 36; // 64c x 64n tiles per batch
    if (bid >= BATCH * TPB) {
        const int wb = bid - BATCH * TPB;          // 0..7
        const int base = wb * 8192 + t;
        #pragma unroll
        for (int i = 0; i < 32; ++i)
            Wbf[base + i * 256] = f2bf(Ww[base + i * 256]);
        return;
    }
    const int b    = bid / TPB;
    const int tile = bid % TPB;
    const int c0   = (tile / 36) * 64;
    const int n0   = (tile % 36) * 64;
    __shared__ float ld[64][65];
    {
        const int row = t >> 2, seg = t & 3;
        const float* src = x + ((size_t)b * CH + c0 + row) * NN + n0 + seg * 16;
        #pragma unroll
        for (int q = 0; q < 4; ++q) {
            float4 v = *reinterpret_cast<const float4*>(src + q * 4);
            ld[row][seg * 16 + q * 4 + 0] = v.x;
            ld[row][seg * 16 + q * 4 + 1] = v.y;
            ld[row][seg * 16 + q * 4 + 2] = v.z;
            ld[row][seg * 16 + q * 4 + 3] = v.w;
        }
    }
    __syncthreads();
    {
        const int j = t >> 2, cs = t & 3;
        u16x8 v0, v1;
        #pragma unroll
        for (int k = 0; k < 8; ++k) v0[k] = f2bf(ld[cs * 16 + k][j]);
        #pragma unroll
        for (int k = 0; k < 8; ++k) v1[k] = f2bf(ld[cs * 16 + 8 + k][j]);
        unsigned short* dst = Xt + ((size_t)b * NN + n0 + j) * CH + c0 + cs * 16;
        *reinterpret_cast<u16x8*>(dst)     = v0;
        *reinterpret_cast<u16x8*>(dst + 8) = v1;
    }
}

// ---------------- Kernel C: Zc[b][o][n] = sum_c W[o][c] x[b][c][n]  (bf16 out) ----------------
__global__ __launch_bounds__(256) void kconv(
    const unsigned short* __restrict__ Xt,
    const unsigned short* __restrict__ Wb,
    unsigned short* __restrict__ Zc)
{
    const int bid  = blockIdx.x;   // 288 = 8b * 4ot * 9nt
    const int b    = bid & 7;
    const int rest = bid >> 3;     // 0..35
    const int ot   = rest / 9;
    const int nt   = rest % 9;
    const int tid  = threadIdx.x;
    const int lane = tid & 63, w = tid >> 6;
    const int lr = lane & 15, lg = lane >> 4;
    const int ob = ot * 64;
    const int nb = nt * 256 + w * 64;

    f32x4 acc[4][4];
    f32x4 z = {0.f, 0.f, 0.f, 0.f};
    #pragma unroll
    for (int og = 0; og < 4; ++og)
        #pragma unroll
        for (int ng = 0; ng < 4; ++ng) acc[og][ng] = z;

    const unsigned short* wp = Wb + (size_t)(ob + lr) * CH + lg * 8;
    const unsigned short* xp = Xt + ((size_t)b * NN + nb + lr) * CH + lg * 8;
    #pragma unroll 1
    for (int kc = 0; kc < 8; ++kc) {
        bf16x8 af[4], bf[4];
        #pragma unroll
        for (int og = 0; og < 4; ++og)
            af[og] = *reinterpret_cast<const bf16x8*>(wp + (size_t)og * 16 * CH + kc * 32);
        #pragma unroll
        for (int ng = 0; ng < 4; ++ng)
            bf[ng] = *reinterpret_cast<const bf16x8*>(xp + (size_t)ng * 16 * CH + kc * 32);
        #pragma unroll
        for (int og = 0; og < 4; ++og)
            #pragma unroll
            for (int ng = 0; ng < 4; ++ng)
                acc[og][ng] = __builtin_amdgcn_mfma_f32_16x16x32_bf16(af[og], bf[ng], acc[og][ng], 0, 0, 0);
    }
    #pragma unroll
    for (int og = 0; og < 4; ++og)
        #pragma unroll
        for (int ng = 0; ng < 4; ++ng)
            #pragma unroll
            for (int r = 0; r < 4; ++r)
                Zc[((size_t)b * CH + ob + og * 16 + lg * 4 + r) * NN + nb + ng * 16 + lr] =
                    f2bf(acc[og][ng][r]);
}

// pack P^T B-fragment from s-regs (verified shuffle net), fixed-shift softmax
static __device__ inline bf16x8 packP(f32x4 s0, f32x4 s1, float sd, float& lsum,
                                      int lr, int lg) {
    float p0[4], p1[4];
    #pragma unroll
    for (int r = 0; r < 4; ++r) {
        p0[r] = __expf(s0[r] - sd);
        p1[r] = __expf(s1[r] - sd);
        lsum += p0[r] + p1[r];
    }
    unsigned u0 = pk2(p0[0], p0[1]), u1 = pk2(p0[2], p0[3]);
    unsigned u2 = pk2(p1[0], p1[1]), u3 = pk2(p1[2], p1[3]);
    int s0l = lr + ((lg & 1) << 5);
    unsigned a0 = (unsigned)__shfl((int)u0, s0l),      c0 = (unsigned)__shfl((int)u2, s0l);
    unsigned a1 = (unsigned)__shfl((int)u1, s0l),      c1 = (unsigned)__shfl((int)u3, s0l);
    unsigned a2 = (unsigned)__shfl((int)u0, s0l + 16), c2 = (unsigned)__shfl((int)u2, s0l + 16);
    unsigned a3 = (unsigned)__shfl((int)u1, s0l + 16), c3 = (unsigned)__shfl((int)u3, s0l + 16);
    bool hi = (lg >= 2);
    u32x4 pw;
    pw[0] = hi ? c0 : a0;
    pw[1] = hi ? c1 : a1;
    pw[2] = hi ? c2 : a2;
    pw[3] = hi ? c3 : a3;
    return __builtin_bit_cast(bf16x8, pw);
}

// ---------------- Kernel A: flash attention, fixed-shift softmax, 32q/wave, kv-split-2 ----------------
// 288 blocks = 8b * 18qt * 2kvh; 4 waves * 32q = 128q per block; 36 iters of 32 keys.
// Writes additive partials pA (bf16) + pL (f32); kmerge combines.
__global__ __launch_bounds__(256, 2) void kattn(
    const unsigned short* __restrict__ Xt,
    const unsigned short* __restrict__ Zc,
    unsigned short* __restrict__ pA,
    float* __restrict__ pL)
{
    __shared__ __attribute__((aligned(16))) unsigned char smem[2][32768];

    const int bid  = blockIdx.x;   // 288
    const int b    = bid & 7;      // batch -> XCD pin
    const int r    = bid >> 3;     // 0..35
    const int qt   = r >> 1;       // 0..17
    const int h    = r & 1;        // kv half
    const int tid  = threadIdx.x;
    const int lane = tid & 63;
    const int w    = tid >> 6;     // wave 0..3
    const int lr = lane & 15;
    const int lg = lane >> 4;
    const int qbase = qt * 128 + w * 32;

    const unsigned short* xtb = Xt + (size_t)b * NN * CH;
    const char* kSrc = (const char*)xtb + (size_t)h * KVH * 512;
    const char* vSrc = (const char*)(Zc + (size_t)b * CH * NN) + (size_t)h * KVH * 2;

    // per-lane staging offsets: linear LDS dest + inverse-swizzled global src (rule #21)
    int koff[4], voff[4];
    #pragma unroll
    for (int i = 0; i < 4; ++i) {
        int p = w * 4096 + i * 1024 + lane * 16;
        int krow = p >> 9, kc_ = p & 511;
        koff[i] = krow * 512 + (kc_ ^ ((krow & 15) << 4));
        int o = p >> 6, vc = p & 63;
        voff[i] = o * 4608 + (vc ^ (((o >> 1) & 3) << 4));
    }

    // Q fragments for two 16q subtiles
    bf16x8 qa0[8], qa1[8];
    {
        const unsigned short* qp0 = xtb + (size_t)(qbase + lr) * CH + lg * 8;
        const unsigned short* qp1 = xtb + (size_t)(qbase + 16 + lr) * CH + lg * 8;
        #pragma unroll
        for (int kc = 0; kc < 8; ++kc) {
            qa0[kc] = *reinterpret_cast<const bf16x8*>(qp0 + kc * 32);
            qa1[kc] = *reinterpret_cast<const bf16x8*>(qp1 + kc * 32);
        }
    }
    // fixed softmax shift: sd[t] = ||q||^2 computed from the SAME bf16 fragments
    float sd0 = 0.f, sd1 = 0.f;
    #pragma unroll
    for (int kc = 0; kc < 8; ++kc)
        #pragma unroll
        for (int j = 0; j < 8; ++j) {
            float v0 = (float)qa0[kc][j];
            float v1 = (float)qa1[kc][j];
            sd0 = fmaf(v0, v0, sd0);
            sd1 = fmaf(v1, v1, sd1);
        }
    sd0 += __shfl_xor(sd0, 16); sd0 += __shfl_xor(sd0, 32);
    sd1 += __shfl_xor(sd1, 16); sd1 += __shfl_xor(sd1, 32);

    f32x4 acc0[16], acc1[16];
    f32x4 zz = {0.f, 0.f, 0.f, 0.f};
    #pragma unroll
    for (int og = 0; og < 16; ++og) { acc0[og] = zz; acc1[og] = zz; }
    float ls0 = 0.f, ls1 = 0.f;

    const int kx = lr << 4;
    const int vx = (lg * 16) ^ (((lr >> 1) & 3) << 4);

    // prologue: stage tile 0 into buf 0
    {
        unsigned char* kb = &smem[0][w * 4096];
        unsigned char* vb = &smem[0][16384 + w * 4096];
        #pragma unroll
        for (int i = 0; i < 4; ++i) GLOAD_LDS(kSrc + koff[i], kb + i * 1024);
        #pragma unroll
        for (int i = 0; i < 4; ++i) GLOAD_LDS(vSrc + voff[i], vb + i * 1024);
    }
    __syncthreads();

    int cur = 0;
    #pragma unroll 1
    for (int ti = 0; ti < NIT; ++ti) {
        if (ti + 1 < NIT) {
            const char* ks = kSrc + (size_t)(ti + 1) * KVB * 512;
            const char* vs = vSrc + (size_t)(ti + 1) * KVB * 2;
            unsigned char* kb = &smem[cur ^ 1][w * 4096];
            unsigned char* vb = &smem[cur ^ 1][16384 + w * 4096];
            #pragma unroll
            for (int i = 0; i < 4; ++i) GLOAD_LDS(ks + koff[i], kb + i * 1024);
            #pragma unroll
            for (int i = 0; i < 4; ++i) GLOAD_LDS(vs + voff[i], vb + i * 1024);
        }

        const unsigned char* kbuf = smem[cur];
        const unsigned char* vbuf = smem[cur] + 16384;

        // S^T = mfma(K, Q) for both q-subtiles
        f32x4 s00 = zz, s01 = zz, s10 = zz, s11 = zz;
        #pragma unroll
        for (int kc = 0; kc < 8; ++kc) {
            bf16x8 k0 = *reinterpret_cast<const bf16x8*>(kbuf + lr * 512        + ((lg * 16 + kc * 64) ^ kx));
            bf16x8 k1 = *reinterpret_cast<const bf16x8*>(kbuf + lr * 512 + 8192 + ((lg * 16 + kc * 64) ^ kx));
            s00 = __builtin_amdgcn_mfma_f32_16x16x32_bf16(k0, qa0[kc], s00, 0, 0, 0);
            s01 = __builtin_amdgcn_mfma_f32_16x16x32_bf16(k1, qa0[kc], s01, 0, 0, 0);
            s10 = __builtin_amdgcn_mfma_f32_16x16x32_bf16(k0, qa1[kc], s10, 0, 0, 0);
            s11 = __builtin_amdgcn_mfma_f32_16x16x32_bf16(k1, qa1[kc], s11, 0, 0, 0);
        }

        // fixed-shift softmax + P^T pack (no max tracking, no rescale)
        bf16x8 pb0 = packP(s00, s01, sd0, ls0, lr, lg);
        bf16x8 pb1 = packP(s10, s11, sd1, ls1, lr, lg);

        // PV: each V fragment feeds both q-subtiles
        #pragma unroll
        for (int og = 0; og < 16; ++og) {
            bf16x8 vb = *reinterpret_cast<const bf16x8*>(vbuf + (og * 16 + lr) * 64 + vx);
            acc0[og] = __builtin_amdgcn_mfma_f32_16x16x32_bf16(vb, pb0, acc0[og], 0, 0, 0);
            acc1[og] = __builtin_amdgcn_mfma_f32_16x16x32_bf16(vb, pb1, acc1[og], 0, 0, 0);
        }

        __syncthreads();
        cur ^= 1;
    }

    // reduce per-lane partial l over the 4 lane-groups (order-free: fixed shift)
    ls0 += __shfl_xor(ls0, 16); ls0 += __shfl_xor(ls0, 32);
    ls1 += __shfl_xor(ls1, 16); ls1 += __shfl_xor(ls1, 32);

    // write partials
    if (lg == 0) {
        pL[(size_t)(h * 8 + b) * NN + qbase + lr]      = ls0;
        pL[(size_t)(h * 8 + b) * NN + qbase + 16 + lr] = ls1;
    }
    const size_t pbase = (size_t)(h * 8 + b) * 256;
    #pragma unroll
    for (int og = 0; og < 16; ++og) {
        #pragma unroll
        for (int rr = 0; rr < 4; ++rr) {
            const int o = og * 16 + lg * 4 + rr;
            pA[(pbase + o) * NN + qbase + lr]      = f2bf(acc0[og][rr]);
            pA[(pbase + o) * NN + qbase + 16 + lr] = f2bf(acc1[og][rr]);
        }
    }
}

// ---------------- Kernel M: out = (A0+A1)/(L0+L1) + bias + x ----------------
__global__ __launch_bounds__(256) void kmerge(
    const unsigned short* __restrict__ pA, const float* __restrict__ pL,
    const float* __restrict__ x, const float* __restrict__ bias,
    float* __restrict__ out)
{
    const int b = blockIdx.x >> 8;
    const int o = blockIdx.x & 255;
    const float bo = bias[o];
    const size_t a0 = ((size_t)b * 256 + o) * NN;
    const size_t a1 = ((size_t)(8 + b) * 256 + o) * NN;
    const float* l0 = pL + (size_t)b * NN;
    const float* l1 = pL + (size_t)(8 + b) * NN;
    const size_t xb = ((size_t)b * 256 + o) * NN;
    #pragma unroll
    for (int k = 0; k < 9; ++k) {
        const int n = k * 256 + threadIdx.x;
        const float v0 = bf2f(pA[a0 + n]);
        const float v1 = bf2f(pA[a1 + n]);
        out[xb + n] = (v0 + v1) / (l0[n] + l1[n]) + bo + x[xb + n];
    }
}

extern "C" void kernel_launch(void* const* d_in, const int* in_sizes, int n_in,
                              void* d_out, int out_size, void* d_ws, size_t ws_size,
                              hipStream_t stream) {
    const float* x    = (const float*)d_in[0];
    const float* Ww   = (const float*)d_in[1];
    const float* bias = (const float*)d_in[2];
    float* out = (float*)d_out;

    unsigned short* Xt  = (unsigned short*)d_ws;                 // B*N*C bf16   (4,718,592)
    unsigned short* Zc  = Xt + (size_t)BATCH * NN * CH;          // B*C*N bf16   (4,718,592)
    unsigned short* Wbf = Zc + (size_t)BATCH * NN * CH;          // C*C bf16     (65,536)
    unsigned short* pA  = Wbf + (size_t)CH * CH;                 // 2*B*C*N bf16 (9,437,184)
    float*          pL  = (float*)(pA + (size_t)2 * BATCH * CH * NN); // 2*B*N f32

    ktrans<<<8 * 144 + 8, 256, 0, stream>>>(x, Ww, Xt, Wbf);
    kconv <<<288,        256, 0, stream>>>(Xt, Wbf, Zc);
    kattn <<<288,        256, 0, stream>>>(Xt, Zc, pA, pL);
    kmerge<<<2048,       256, 0, stream>>>(pA, pL, x, bias, out);
}